// Round 15
// baseline (184.273 us; speedup 1.0000x reference)
//
#include <hip/hip_runtime.h>

// 2-layer LSTM, B=4096, S=512, F=8, H=10 + FC(10->1) on last step.
// R14: single self-contained wave does BOTH layers for 3 elements.
//  - 6x 10-lane groups: groups 0-2 = L0 role (elems a,b,c), groups 3-5 =
//    L1 role (same elems, lag 2). Handoff via 4-slot LDS h0 buffer,
//    intra-wave (DS ops in-order within a wave) -> ZERO barriers.
//  - uniform instruction stream: 5 input-pair dots + 5 recurrent-pair dots
//    x 4 gates (L0's x padded to 5 pairs w/ zero weights); input selected
//    per-role with 4 cndmask (x regs vs prefetched slot read).
//  - all DS consumers prefetched one body ahead (recurrent readback +
//    input slot read issued at body end) -> no mid-body lgkm stalls.
//  - 64-thr blocks (1 wave), 1366 blocks; lane-local acts (no bperm).
// Weights f16 (L2E/2L2E prescaled), accum/acts/c f32 (R13 numerics).

typedef __fp16 v2h __attribute__((ext_vector_type(2)));
typedef __fp16 v8h __attribute__((ext_vector_type(8)));
struct h4 { v2h a, b, c, d; };

#define L2E 1.4426950408889634f

__device__ __forceinline__ v2h pkh(float a, float b) {
    return __builtin_amdgcn_cvt_pkrtz(a, b);
}

#define SIGM(a)  __builtin_amdgcn_rcpf(1.0f + __builtin_amdgcn_exp2f(-(a)))
#define TANHP(a) fmaf(-2.0f, __builtin_amdgcn_rcpf(1.0f + __builtin_amdgcn_exp2f(a)), 1.0f)
#define DOT2(acc, w, v) (acc) = __builtin_amdgcn_fdot2((w), (v), (acc), false)

// TBAA-safe packed row read (PTR __fp16*, 16B aligned): 10 halves
#define READROW(PTR, H)                                                      \
    { v8h w0_ = *(const v8h*)(PTR);                                          \
      v2h w1_ = *(const v2h*)((PTR) + 8);                                    \
      h4 q_ = __builtin_bit_cast(h4, w0_);                                   \
      H[0]=q_.a; H[1]=q_.b; H[2]=q_.c; H[3]=q_.d; H[4]=w1_; }

__global__ __launch_bounds__(64, 2)
void lstm2_r14(const float* __restrict__ x,
               const float* __restrict__ hid,
               const float* __restrict__ cel,
               const float* __restrict__ Wih0, const float* __restrict__ Whh0,
               const float* __restrict__ bih0, const float* __restrict__ bhh0,
               const float* __restrict__ Wih1, const float* __restrict__ Whh1,
               const float* __restrict__ bih1, const float* __restrict__ bhh1,
               const float* __restrict__ Wfc,  const float* __restrict__ bfc,
               float* __restrict__ out)
{
    __shared__ __attribute__((aligned(16))) __fp16 h0s[4][3][16]; // 384 B
    __shared__ __attribute__((aligned(16))) __fp16 h1w[3][16];    // 96 B
    __shared__ float fcb[3][10];

    const int lane = threadIdx.x & 63;
    int g = lane / 10, j = lane - (lane / 10) * 10;
    if (lane >= 60) { g = 5; j = 9; }       // pad lanes dupe lane 59
    const bool role = (g >= 3);             // true = L1 role
    const int  ge   = role ? g - 3 : g;     // element index in wave, 0..2
    const int  e    = blockIdx.x * 3 + ge;  // 1366*3 = 4098 (2 pad)
    const int  ec   = (e < 4095) ? e : 4095;
    const bool st   = (lane < 60) && (e < 4096);

    // ---- weights: w[q][0..4]=input pairs, w[q][5..9]=recurrent pairs ----
    v2h w[4][10]; float bb[4];
    #pragma unroll
    for (int q = 0; q < 4; ++q) {
        const int r = q * 10 + j;
        const float sc = (q == 2) ? 2.0f * L2E : L2E;
        if (role) {
            #pragma unroll
            for (int k = 0; k < 5; ++k) {
                w[q][k]   = pkh(Wih1[r*10+2*k]*sc, Wih1[r*10+2*k+1]*sc);
                w[q][5+k] = pkh(Whh1[r*10+2*k]*sc, Whh1[r*10+2*k+1]*sc);
            }
            bb[q] = (bih1[r] + bhh1[r]) * sc;
        } else {
            #pragma unroll
            for (int k = 0; k < 4; ++k)
                w[q][k] = pkh(Wih0[r*8+2*k]*sc, Wih0[r*8+2*k+1]*sc);
            w[q][4] = pkh(0.0f, 0.0f);
            #pragma unroll
            for (int k = 0; k < 5; ++k)
                w[q][5+k] = pkh(Whh0[r*10+2*k]*sc, Whh0[r*10+2*k+1]*sc);
            bb[q] = (bih0[r] + bhh0[r]) * sc;
        }
    }
    const float wfc = Wfc[j];

    // ---- state per role ----
    const float* hb = hid + (role ? 40960 : 0);
    const float* cb = cel + (role ? 40960 : 0);
    v2h hv[5];
    #pragma unroll
    for (int k = 0; k < 5; ++k) hv[k] = pkh(hb[ec*10+2*k], hb[ec*10+2*k+1]);
    float cc = cb[ec*10 + j];
    float hj = hb[ec*10 + j];

    // ---- per-lane LDS addresses ----
    __fp16* wrj[4]; const __fp16* rb[4]; const __fp16* ain[4];
    #pragma unroll
    for (int p = 0; p < 4; ++p) {
        __fp16* own = role ? &h1w[ge][0] : &h0s[p][ge][0];
        wrj[p] = own + j;
        rb[p]  = own;
        ain[p] = &h0s[p][ge][0];
    }
    if (role) h1w[ge][j] = (__fp16)hj;   // initial h1 row for first readbacks

    // ---- x buffers (x[t] at xp4[2t..2t+1]) ----
    const float4* __restrict__ xp4 = reinterpret_cast<const float4*>(x + (size_t)ec * 4096);
    float4 xa[2], xb[2], xc[2], xd[2];
    xa[0]=xp4[0]; xa[1]=xp4[1];  xb[0]=xp4[2]; xb[1]=xp4[3];
    xc[0]=xp4[4]; xc[1]=xp4[5];  xd[0]=xp4[6]; xd[1]=xp4[7];

    // prefetched next-body inputs: sl (slot read), xin (x unpack)
    v2h sl[5], xin[5];
    #pragma unroll
    for (int k = 0; k < 5; ++k) sl[k] = pkh(0.0f, 0.0f);
    xin[0]=pkh(xa[0].x,xa[0].y); xin[1]=pkh(xa[0].z,xa[0].w);
    xin[2]=pkh(xa[1].x,xa[1].y); xin[3]=pkh(xa[1].z,xa[1].w);
    xin[4]=pkh(0.0f,0.0f);

// Body n: consume prefetched (sl,xin,hv); write slot P; prefetch rb[P],
// ain[PIN], unpack XBN (x[n+1]), refill XBR <- x[min(TN,511)].
// SUP: 0 none, 1 suppress L1 update (n<2), 2 suppress L0 update (n>511).
#define BODY(XBN, XBR, P, PIN, TN, SUP, DOREF)                               \
    {                                                                        \
        v2h in0 = role ? sl[0] : xin[0];                                     \
        v2h in1 = role ? sl[1] : xin[1];                                     \
        v2h in2 = role ? sl[2] : xin[2];                                     \
        v2h in3 = role ? sl[3] : xin[3];                                     \
        v2h in4 = sl[4];               /* L0 weight w[q][4]=0 */             \
        float aI=bb[0], aF=bb[1], aG=bb[2], aO=bb[3];                        \
        DOT2(aI,w[0][0],in0); DOT2(aF,w[1][0],in0);                          \
        DOT2(aG,w[2][0],in0); DOT2(aO,w[3][0],in0);                          \
        DOT2(aI,w[0][1],in1); DOT2(aF,w[1][1],in1);                          \
        DOT2(aG,w[2][1],in1); DOT2(aO,w[3][1],in1);                          \
        DOT2(aI,w[0][2],in2); DOT2(aF,w[1][2],in2);                          \
        DOT2(aG,w[2][2],in2); DOT2(aO,w[3][2],in2);                          \
        DOT2(aI,w[0][3],in3); DOT2(aF,w[1][3],in3);                          \
        DOT2(aG,w[2][3],in3); DOT2(aO,w[3][3],in3);                          \
        DOT2(aI,w[0][4],in4); DOT2(aF,w[1][4],in4);                          \
        DOT2(aG,w[2][4],in4); DOT2(aO,w[3][4],in4);                          \
        _Pragma("unroll")                                                    \
        for (int k = 0; k < 5; ++k) {                                        \
            DOT2(aI,w[0][5+k],hv[k]); DOT2(aF,w[1][5+k],hv[k]);              \
            DOT2(aG,w[2][5+k],hv[k]); DOT2(aO,w[3][5+k],hv[k]);              \
        }                                                                    \
        float i_=SIGM(aI), f_=SIGM(aF), g_=TANHP(aG), o_=SIGM(aO);           \
        float ncc = fmaf(f_, cc, i_ * g_);                                   \
        float nhj = o_ * TANHP((2.0f*L2E) * ncc);                            \
        if (SUP == 1) { ncc = role ? cc : ncc; nhj = role ? hj : nhj; }      \
        if (SUP == 2) { ncc = role ? ncc : cc; nhj = role ? nhj : hj; }      \
        cc = ncc; hj = nhj;                                                  \
        *wrj[P] = (__fp16)hj;                                                \
        READROW(rb[P], hv)                                                   \
        READROW(ain[PIN], sl)                                                \
        xin[0]=pkh(XBN[0].x,XBN[0].y); xin[1]=pkh(XBN[0].z,XBN[0].w);        \
        xin[2]=pkh(XBN[1].x,XBN[1].y); xin[3]=pkh(XBN[1].z,XBN[1].w);        \
        if (DOREF) { int tn=(TN)>511?511:(TN);                               \
                     XBR[0]=xp4[2*tn]; XBR[1]=xp4[2*tn+1]; }                 \
    }

    // prologue bodies n=0,1 (L1 update suppressed)
    BODY(xb, xa, 0, 3, 4, 1, 1)
    BODY(xc, xb, 1, 0, 5, 1, 1)
    // main: n = 2..509, 127 iters x 4 bodies
    for (int it = 0; it < 127; ++it) {
        const int tb = 4 * it;
        BODY(xd, xc, 2, 1, tb + 6, 0, 1)   // n = tb+2
        BODY(xa, xd, 3, 2, tb + 7, 0, 1)   // n = tb+3
        BODY(xb, xa, 0, 3, tb + 8, 0, 1)   // n = tb+4
        BODY(xc, xb, 1, 0, tb + 9, 0, 1)   // n = tb+5
    }
    // epilogue: n=510,511 (full), n=512,513 (L0 update suppressed)
    BODY(xd, xc, 2, 1, 511, 0, 0)
    BODY(xa, xd, 3, 2, 511, 0, 0)
    BODY(xb, xa, 0, 3, 511, 2, 0)
    BODY(xc, xb, 1, 0, 511, 2, 0)
#undef BODY

    // ---- outputs: [0,4096) fc | h l0,l1 | c l0,l1 ----
    if (!role) {
        if (st) {
            out[4096          + e * 10 + j] = hj;   // h0_T
            out[4096 + 81920  + e * 10 + j] = cc;   // c0_T
        }
    } else {
        fcb[ge][j] = hj * wfc;                       // same-wave DS, in-order
        if (st) {
            out[4096 + 40960  + e * 10 + j] = hj;   // h1_T
            out[4096 + 122880 + e * 10 + j] = cc;   // c1_T
        }
        if (st && j == 0) {
            float p = bfc[0];
            #pragma unroll
            for (int k = 0; k < 10; ++k) p += fcb[ge][k];
            out[e] = p;
        }
    }
}

extern "C" void kernel_launch(void* const* d_in, const int* in_sizes, int n_in,
                              void* d_out, int out_size, void* d_ws, size_t ws_size,
                              hipStream_t stream) {
    const float* x    = (const float*)d_in[0];
    const float* hid  = (const float*)d_in[1];
    const float* cel  = (const float*)d_in[2];
    const float* Wih0 = (const float*)d_in[3];
    const float* Whh0 = (const float*)d_in[4];
    const float* bih0 = (const float*)d_in[5];
    const float* bhh0 = (const float*)d_in[6];
    const float* Wih1 = (const float*)d_in[7];
    const float* Whh1 = (const float*)d_in[8];
    const float* bih1 = (const float*)d_in[9];
    const float* bhh1 = (const float*)d_in[10];
    const float* Wfc  = (const float*)d_in[11];
    const float* bfc  = (const float*)d_in[12];

    // 1366 blocks x 64 thr (one self-contained wave per block, 3 elements)
    hipLaunchKernelGGL(lstm2_r14, dim3(1366), dim3(64), 0, stream,
                       x, hid, cel, Wih0, Whh0, bih0, bhh0,
                       Wih1, Whh1, bih1, bhh1, Wfc, bfc,
                       (float*)d_out);
}